// Round 1
// baseline (3667.723 us; speedup 1.0000x reference)
//
#include <hip/hip_runtime.h>
#include <math.h>

#define D_MODEL 256
#define NSEQ    2048
#define BATCH   4
#define NHEAD   8
#define HDIM    32

// ---------------------------------------------------------------------------
// GEMM: C[M][N] = A[M][K] @ W[N][K]^T + bias[N]   (torch Linear convention)
// fp32, 64x64 tile, BK=16, 256 threads, 4x4 micro-tile.
// ---------------------------------------------------------------------------
__global__ __launch_bounds__(256) void gemm_bias_kernel(
    const float* __restrict__ A, const float* __restrict__ W,
    const float* __restrict__ bias, float* __restrict__ C,
    int M, int N, int K)
{
    __shared__ float As[16][65];  // [k][m], padded stride 65
    __shared__ float Bs[16][65];  // [k][n]

    const int t  = threadIdx.x;
    const int tx = t & 15;        // output col group
    const int ty = t >> 4;        // output row group
    const int m0 = blockIdx.y * 64;
    const int n0 = blockIdx.x * 64;

    const int lr = t >> 2;          // 0..63: tile row loaded by this thread
    const int lk = (t & 3) * 4;     // k-chunk (float4)

    float acc[4][4] = {};

    for (int k0 = 0; k0 < K; k0 += 16) {
        float4 av = *reinterpret_cast<const float4*>(&A[(size_t)(m0 + lr) * K + k0 + lk]);
        float4 wv = *reinterpret_cast<const float4*>(&W[(size_t)(n0 + lr) * K + k0 + lk]);
        As[lk + 0][lr] = av.x; As[lk + 1][lr] = av.y;
        As[lk + 2][lr] = av.z; As[lk + 3][lr] = av.w;
        Bs[lk + 0][lr] = wv.x; Bs[lk + 1][lr] = wv.y;
        Bs[lk + 2][lr] = wv.z; Bs[lk + 3][lr] = wv.w;
        __syncthreads();

        #pragma unroll
        for (int kk = 0; kk < 16; ++kk) {
            float a[4], b[4];
            #pragma unroll
            for (int i = 0; i < 4; ++i) a[i] = As[kk][ty * 4 + i];
            #pragma unroll
            for (int j = 0; j < 4; ++j) b[j] = Bs[kk][tx * 4 + j];
            #pragma unroll
            for (int i = 0; i < 4; ++i)
                #pragma unroll
                for (int j = 0; j < 4; ++j)
                    acc[i][j] = fmaf(a[i], b[j], acc[i][j]);
        }
        __syncthreads();
    }

    #pragma unroll
    for (int i = 0; i < 4; ++i) {
        #pragma unroll
        for (int j = 0; j < 4; ++j) {
            const int n = n0 + tx * 4 + j;
            C[(size_t)(m0 + ty * 4 + i) * N + n] = acc[i][j] + bias[n];
        }
    }
}

// ---------------------------------------------------------------------------
// Flash-style attention, fp32. One wave (64 lanes) per query row.
// Q,K,V,O all in (B, N, D) layout with heads interleaved (D = H*HDIM).
// Per iteration each lane owns one K/V row (64 rows per tile), online softmax.
// ---------------------------------------------------------------------------
__global__ __launch_bounds__(256) void attn_kernel(
    const float* __restrict__ Q, const float* __restrict__ K,
    const float* __restrict__ V, float* __restrict__ O)
{
    __shared__ float red[4][64 * 33];  // per-wave reduction scratch (padded)

    const int wv   = threadIdx.x >> 6;
    const int lane = threadIdx.x & 63;
    const int w    = blockIdx.x * 4 + wv;           // global row id
    const int b    = w / (NHEAD * NSEQ);
    const int h    = (w / NSEQ) % NHEAD;
    const int q    = w % NSEQ;

    const float* qrow  = Q + ((size_t)(b * NSEQ + q)) * D_MODEL + h * HDIM;
    const float* Kbase = K + (size_t)b * NSEQ * D_MODEL + h * HDIM;
    const float* Vbase = V + (size_t)b * NSEQ * D_MODEL + h * HDIM;

    // q row in registers (all lanes hold the full row)
    float4 qv[8];
    #pragma unroll
    for (int i = 0; i < 8; ++i)
        qv[i] = *reinterpret_cast<const float4*>(qrow + i * 4);

    float4 o4[8];
    #pragma unroll
    for (int i = 0; i < 8; ++i) o4[i] = make_float4(0.f, 0.f, 0.f, 0.f);

    float mrun = -INFINITY;
    float lsum = 0.f;
    const float sc = 0.17677669529663687f;  // 1/sqrt(32)

    for (int kt = 0; kt < NSEQ / 64; ++kt) {
        const int k = kt * 64 + lane;
        const float* krow = Kbase + (size_t)k * D_MODEL;

        float s = 0.f;
        #pragma unroll
        for (int i = 0; i < 8; ++i) {
            float4 kv = *reinterpret_cast<const float4*>(krow + i * 4);
            s = fmaf(qv[i].x, kv.x, s);
            s = fmaf(qv[i].y, kv.y, s);
            s = fmaf(qv[i].z, kv.z, s);
            s = fmaf(qv[i].w, kv.w, s);
        }
        s *= sc;

        // wave max
        float tm = s;
        #pragma unroll
        for (int off = 32; off >= 1; off >>= 1)
            tm = fmaxf(tm, __shfl_xor(tm, off));
        const float mnew  = fmaxf(mrun, tm);
        const float scale = __expf(mrun - mnew);   // exp(-inf - finite) = 0 on first tile
        const float p     = __expf(s - mnew);

        float ts = p;
        #pragma unroll
        for (int off = 32; off >= 1; off >>= 1)
            ts += __shfl_xor(ts, off);
        lsum = lsum * scale + ts;

        const float* vrow = Vbase + (size_t)k * D_MODEL;
        #pragma unroll
        for (int i = 0; i < 8; ++i) {
            float4 vvv = *reinterpret_cast<const float4*>(vrow + i * 4);
            o4[i].x = fmaf(p, vvv.x, o4[i].x * scale);
            o4[i].y = fmaf(p, vvv.y, o4[i].y * scale);
            o4[i].z = fmaf(p, vvv.z, o4[i].z * scale);
            o4[i].w = fmaf(p, vvv.w, o4[i].w * scale);
        }
        mrun = mnew;
    }

    // cross-lane reduce of the 32 output dims via padded LDS
    #pragma unroll
    for (int i = 0; i < 8; ++i) {
        red[wv][lane * 33 + i * 4 + 0] = o4[i].x;
        red[wv][lane * 33 + i * 4 + 1] = o4[i].y;
        red[wv][lane * 33 + i * 4 + 2] = o4[i].z;
        red[wv][lane * 33 + i * 4 + 3] = o4[i].w;
    }
    __syncthreads();

    if (lane < 32) {
        float sum = 0.f;
        #pragma unroll 8
        for (int j = 0; j < 64; ++j)
            sum += red[wv][j * 33 + lane];
        O[((size_t)(b * NSEQ + q)) * D_MODEL + h * HDIM + lane] = sum / lsum;
    }
}

// ---------------------------------------------------------------------------
extern "C" void kernel_launch(void* const* d_in, const int* in_sizes, int n_in,
                              void* d_out, int out_size, void* d_ws, size_t ws_size,
                              hipStream_t stream)
{
    const float* x  = (const float*)d_in[0];
    const float* Wq = (const float*)d_in[1];
    const float* bq = (const float*)d_in[2];
    const float* Wk = (const float*)d_in[3];
    const float* bk = (const float*)d_in[4];
    const float* Wv = (const float*)d_in[5];
    const float* bv = (const float*)d_in[6];
    const float* Wo = (const float*)d_in[7];
    const float* bo = (const float*)d_in[8];
    float* out = (float*)d_out;

    const size_t MT = (size_t)BATCH * NSEQ;  // 8192 rows
    float* Qb = (float*)d_ws;
    float* Kb = Qb + MT * D_MODEL;
    float* Vb = Kb + MT * D_MODEL;
    float* Ab = Vb + MT * D_MODEL;

    dim3 gg(D_MODEL / 64, MT / 64);  // (4, 128)
    gemm_bias_kernel<<<gg, 256, 0, stream>>>(x, Wq, bq, Qb, (int)MT, D_MODEL, D_MODEL);
    gemm_bias_kernel<<<gg, 256, 0, stream>>>(x, Wk, bk, Kb, (int)MT, D_MODEL, D_MODEL);
    gemm_bias_kernel<<<gg, 256, 0, stream>>>(x, Wv, bv, Vb, (int)MT, D_MODEL, D_MODEL);

    attn_kernel<<<(BATCH * NHEAD * NSEQ) / 4, 256, 0, stream>>>(Qb, Kb, Vb, Ab);

    gemm_bias_kernel<<<gg, 256, 0, stream>>>(Ab, Wo, bo, out, (int)MT, D_MODEL, D_MODEL);
}

// Round 2
// 124.045 us; speedup vs baseline: 29.5676x; 29.5676x over previous
//
#include <hip/hip_runtime.h>
#include <math.h>

#define D_MODEL 256
#define NSEQ    2048
#define BATCH   4
#define NHEAD   8
#define HDIM    32

typedef __attribute__((ext_vector_type(8))) short  short8;   // 8 bf16 (4 VGPRs)
typedef __attribute__((ext_vector_type(4))) float  f32x4;
typedef __attribute__((ext_vector_type(4))) unsigned short us4;
typedef __attribute__((ext_vector_type(4))) unsigned int   u32x4;
typedef unsigned short u16;
typedef unsigned int   u32;

__device__ __forceinline__ u16 f2bf(float f) {
    union { float f; u32 u; } v; v.f = f;
    u32 r = v.u + 0x7FFFu + ((v.u >> 16) & 1u);   // RNE
    return (u16)(r >> 16);
}

// ---------------------------------------------------------------------------
// fp32 -> bf16 converts (x: 2,097,152 elems; W: 4 x 65,536 elems)
// ---------------------------------------------------------------------------
__global__ __launch_bounds__(256) void cvt_x_kernel(const float* __restrict__ src,
                                                    u16* __restrict__ dst, int n8) {
    int i = blockIdx.x * 256 + threadIdx.x;
    if (i >= n8) return;
    const float4* s4 = (const float4*)src;
    float4 a = s4[2 * i], b = s4[2 * i + 1];
    u32x4 o;
    o.x = f2bf(a.x) | ((u32)f2bf(a.y) << 16);
    o.y = f2bf(a.z) | ((u32)f2bf(a.w) << 16);
    o.z = f2bf(b.x) | ((u32)f2bf(b.y) << 16);
    o.w = f2bf(b.z) | ((u32)f2bf(b.w) << 16);
    *(u32x4*)(dst + (size_t)i * 8) = o;
}

__global__ __launch_bounds__(256) void cvt_w_kernel(const float* __restrict__ w0,
                                                    const float* __restrict__ w1,
                                                    const float* __restrict__ w2,
                                                    const float* __restrict__ w3,
                                                    u16* __restrict__ dst) {
    int which = blockIdx.y;
    const float* src = which == 0 ? w0 : which == 1 ? w1 : which == 2 ? w2 : w3;
    u16* d = dst + (size_t)which * 65536;
    int i = blockIdx.x * 256 + threadIdx.x;   // 0..8191
    const float4* s4 = (const float4*)src;
    float4 a = s4[2 * i], b = s4[2 * i + 1];
    u32x4 o;
    o.x = f2bf(a.x) | ((u32)f2bf(a.y) << 16);
    o.y = f2bf(a.z) | ((u32)f2bf(a.w) << 16);
    o.z = f2bf(b.x) | ((u32)f2bf(b.y) << 16);
    o.w = f2bf(b.z) | ((u32)f2bf(b.w) << 16);
    *(u32x4*)(d + (size_t)i * 8) = o;
}

// ---------------------------------------------------------------------------
// Fused QKV GEMM: C = x @ W^T + b, bf16 MFMA, 64x128 tile, 4 waves.
// z = blockIdx.z selects (Wq,bq,Q) / (Wk,bk,K) / (Wv,bv,V).
// Output layout: (B, H, N, HD) bf16 so attention loads are contiguous.
// ---------------------------------------------------------------------------
__global__ __launch_bounds__(256) void gemm_qkv_kernel(
    const u16* __restrict__ xb, const u16* __restrict__ Wall,
    const float* __restrict__ bq, const float* __restrict__ bk,
    const float* __restrict__ bv, u16* __restrict__ QKV)
{
    const int z = blockIdx.z;
    const u16* W = Wall + (size_t)z * 65536;
    const float* bias = z == 0 ? bq : (z == 1 ? bk : bv);
    u16* out = QKV + (size_t)z * 8192 * 256;

    const int wid = threadIdx.x >> 6, l = threadIdx.x & 63;
    const int lq = l & 15, g = l >> 4;
    const int m0 = blockIdx.y * 64 + wid * 16;
    const int n0 = blockIdx.x * 128;

    const u16* Arow = xb + (size_t)(m0 + lq) * 256;

    f32x4 acc[8];
    #pragma unroll
    for (int ns = 0; ns < 8; ++ns) acc[ns] = (f32x4){0.f, 0.f, 0.f, 0.f};

    #pragma unroll
    for (int kk = 0; kk < 8; ++kk) {
        short8 af = *(const short8*)(Arow + kk * 32 + g * 8);
        #pragma unroll
        for (int ns = 0; ns < 8; ++ns) {
            short8 wf = *(const short8*)(W + (size_t)(n0 + ns * 16 + lq) * 256 + kk * 32 + g * 8);
            acc[ns] = __builtin_amdgcn_mfma_f32_16x16x32_bf16(af, wf, acc[ns], 0, 0, 0);
        }
    }

    #pragma unroll
    for (int ns = 0; ns < 8; ++ns) {
        const int n = n0 + ns * 16 + lq;
        const float bb = bias[n];
        const int h = n >> 5, d = n & 31;
        #pragma unroll
        for (int r = 0; r < 4; ++r) {
            const int m = m0 + g * 4 + r;
            const int b = m >> 11, seq = m & 2047;
            out[((size_t)(b * 8 + h) * 2048 + seq) * 32 + d] = f2bf(acc[ns][r] + bb);
        }
    }
}

// ---------------------------------------------------------------------------
// Output GEMM: out = attended @ Wo^T + bo, fp32 stores.
// ---------------------------------------------------------------------------
__global__ __launch_bounds__(256) void gemm_out_kernel(
    const u16* __restrict__ A, const u16* __restrict__ W,
    const float* __restrict__ bias, float* __restrict__ Cout)
{
    const int wid = threadIdx.x >> 6, l = threadIdx.x & 63;
    const int lq = l & 15, g = l >> 4;
    const int m0 = blockIdx.y * 64 + wid * 16;
    const int n0 = blockIdx.x * 128;

    const u16* Arow = A + (size_t)(m0 + lq) * 256;

    f32x4 acc[8];
    #pragma unroll
    for (int ns = 0; ns < 8; ++ns) acc[ns] = (f32x4){0.f, 0.f, 0.f, 0.f};

    #pragma unroll
    for (int kk = 0; kk < 8; ++kk) {
        short8 af = *(const short8*)(Arow + kk * 32 + g * 8);
        #pragma unroll
        for (int ns = 0; ns < 8; ++ns) {
            short8 wf = *(const short8*)(W + (size_t)(n0 + ns * 16 + lq) * 256 + kk * 32 + g * 8);
            acc[ns] = __builtin_amdgcn_mfma_f32_16x16x32_bf16(af, wf, acc[ns], 0, 0, 0);
        }
    }

    #pragma unroll
    for (int ns = 0; ns < 8; ++ns) {
        const int n = n0 + ns * 16 + lq;
        const float bb = bias[n];
        #pragma unroll
        for (int r = 0; r < 4; ++r) {
            const int m = m0 + g * 4 + r;
            Cout[(size_t)m * 256 + n] = acc[ns][r] + bb;
        }
    }
}

// ---------------------------------------------------------------------------
// Flash attention, bf16 MFMA. Block = 4 waves; wave owns 16 q rows; KV tiles
// of 64 keys staged in LDS (shared by the 4 waves). S^T = mfma(K, Q) so the
// softmax per-lane column is one q (lane&15); online softmax; P via per-wave
// LDS tile; PV accumulates fp32 in-register.
// Layouts: Kt stride 40 elems (80B rows, b128-aligned, ~2-way banks);
//          Vt transposed [32 d][72], pair-packed writes (2-way banks);
//          Pl per wave [16 q][72].
// ---------------------------------------------------------------------------
__global__ __launch_bounds__(256) void attn_kernel(
    const u16* __restrict__ Q, const u16* __restrict__ K,
    const u16* __restrict__ V, u16* __restrict__ Oa)
{
    __shared__ u16 Kt[64 * 40];
    __shared__ u16 Vt[32 * 72];
    __shared__ u16 Pl[4][16 * 72];

    const int tid = threadIdx.x;
    const int wid = tid >> 6, l = tid & 63;
    const int lq = l & 15, g = l >> 4;
    const int bh = blockIdx.y;                 // b*8 + h

    const u16* Qb = Q + ((size_t)bh * 2048 + blockIdx.x * 64 + wid * 16) * 32;
    const u16* Kb = K + (size_t)bh * 2048 * 32;
    const u16* Vb = V + (size_t)bh * 2048 * 32;

    // Q B-fragment: col q = lane&15, k(dim) = g*8..g*8+7
    const short8 qf = *(const short8*)(Qb + lq * 32 + g * 8);

    f32x4 o0 = (f32x4){0.f, 0.f, 0.f, 0.f};
    f32x4 o1 = (f32x4){0.f, 0.f, 0.f, 0.f};
    float mrun = -1e30f, lsum = 0.f;
    const float SC = 0.17677669529663687f;     // 1/sqrt(32)

    // staging assignments
    const int krow = tid >> 2, kchk = (tid & 3) * 8;      // K: row, 8-dim chunk
    const int vkp = tid & 31, vd0 = (tid >> 5) * 4;       // V: key pair, 4 dims

    for (int kt = 0; kt < 32; ++kt) {
        // ---- stage K tile (linear [64][40]) ----
        short8 kv = *(const short8*)(Kb + (size_t)(kt * 64 + krow) * 32 + kchk);
        *(short8*)&Kt[krow * 40 + kchk] = kv;
        // ---- stage V tile transposed (Vt[d][k], pair-packed) ----
        us4 va = *(const us4*)(Vb + (size_t)(kt * 64 + 2 * vkp) * 32 + vd0);
        us4 vb2 = *(const us4*)(Vb + (size_t)(kt * 64 + 2 * vkp + 1) * 32 + vd0);
        #pragma unroll
        for (int j = 0; j < 4; ++j)
            *(u32*)&Vt[(vd0 + j) * 72 + 2 * vkp] = (u32)va[j] | ((u32)vb2[j] << 16);
        __syncthreads();

        // ---- S^T = K_tile . Q^T : 4 MFMAs (16 keys each) ----
        f32x4 sf[4];
        #pragma unroll
        for (int s = 0; s < 4; ++s) {
            short8 kf = *(const short8*)&Kt[(s * 16 + lq) * 40 + g * 8];
            sf[s] = __builtin_amdgcn_mfma_f32_16x16x32_bf16(kf, qf, (f32x4){0.f,0.f,0.f,0.f}, 0, 0, 0);
        }

        // ---- online softmax (per lane: q = lq fixed, 16 key scores) ----
        float tm = -1e30f;
        #pragma unroll
        for (int s = 0; s < 4; ++s)
            tm = fmaxf(tm, fmaxf(fmaxf(sf[s][0], sf[s][1]), fmaxf(sf[s][2], sf[s][3])));
        tm = fmaxf(tm, __shfl_xor(tm, 16));
        tm = fmaxf(tm, __shfl_xor(tm, 32));
        const float mnew = fmaxf(mrun, tm);
        const float scl = __expf((mrun - mnew) * SC);

        float tsum = 0.f;
        #pragma unroll
        for (int s = 0; s < 4; ++s) {
            float p0 = __expf((sf[s][0] - mnew) * SC);
            float p1 = __expf((sf[s][1] - mnew) * SC);
            float p2 = __expf((sf[s][2] - mnew) * SC);
            float p3 = __expf((sf[s][3] - mnew) * SC);
            tsum += (p0 + p1) + (p2 + p3);
            const int e = lq * 72 + s * 16 + g * 4;
            *(u32*)&Pl[wid][e]     = (u32)f2bf(p0) | ((u32)f2bf(p1) << 16);
            *(u32*)&Pl[wid][e + 2] = (u32)f2bf(p2) | ((u32)f2bf(p3) << 16);
        }
        tsum += __shfl_xor(tsum, 16);
        tsum += __shfl_xor(tsum, 32);
        lsum = lsum * scl + tsum;
        mrun = mnew;

        // ---- rescale O (per-row q = g*4+r; scl lives in lane q) ----
        #pragma unroll
        for (int r = 0; r < 4; ++r) {
            float sr = __shfl(scl, g * 4 + r);
            o0[r] *= sr; o1[r] *= sr;
        }

        // ---- PV: O[q][d] += P . V ----
        #pragma unroll
        for (int kc = 0; kc < 2; ++kc) {
            short8 pa  = *(const short8*)&Pl[wid][lq * 72 + kc * 32 + g * 8];
            short8 vf0 = *(const short8*)&Vt[lq * 72 + kc * 32 + g * 8];
            short8 vf1 = *(const short8*)&Vt[(16 + lq) * 72 + kc * 32 + g * 8];
            o0 = __builtin_amdgcn_mfma_f32_16x16x32_bf16(pa, vf0, o0, 0, 0, 0);
            o1 = __builtin_amdgcn_mfma_f32_16x16x32_bf16(pa, vf1, o1, 0, 0, 0);
        }
        __syncthreads();
    }

    // ---- epilogue: divide by lsum, store bf16 token-major (B,N,D) ----
    const int b = bh >> 3, h = bh & 7;
    #pragma unroll
    for (int r = 0; r < 4; ++r) {
        float ls = __shfl(lsum, g * 4 + r);
        float inv = 1.0f / ls;
        const int seq = blockIdx.x * 64 + wid * 16 + g * 4 + r;
        const size_t base = ((size_t)(b * 2048 + seq)) * 256 + h * 32;
        Oa[base + lq]      = f2bf(o0[r] * inv);
        Oa[base + 16 + lq] = f2bf(o1[r] * inv);
    }
}

// ---------------------------------------------------------------------------
extern "C" void kernel_launch(void* const* d_in, const int* in_sizes, int n_in,
                              void* d_out, int out_size, void* d_ws, size_t ws_size,
                              hipStream_t stream)
{
    const float* x  = (const float*)d_in[0];
    const float* Wq = (const float*)d_in[1];
    const float* bq = (const float*)d_in[2];
    const float* Wk = (const float*)d_in[3];
    const float* bk = (const float*)d_in[4];
    const float* Wv = (const float*)d_in[5];
    const float* bv = (const float*)d_in[6];
    const float* Wo = (const float*)d_in[7];
    const float* bo = (const float*)d_in[8];
    float* out = (float*)d_out;

    u16* wsp  = (u16*)d_ws;
    u16* xb   = wsp;                          // 8192*256
    u16* Wall = xb + (size_t)8192 * 256;      // 4*65536
    u16* QKV  = Wall + (size_t)4 * 65536;     // 3*8192*256  (B,H,N,HD) each
    u16* Ab   = QKV + (size_t)3 * 8192 * 256; // 8192*256    (B,N,D)

    cvt_x_kernel<<<1024, 256, 0, stream>>>(x, xb, 262144);
    cvt_w_kernel<<<dim3(32, 4), 256, 0, stream>>>(Wq, Wk, Wv, Wo, Wall);

    gemm_qkv_kernel<<<dim3(2, 128, 3), 256, 0, stream>>>(xb, Wall, bq, bk, bv, QKV);

    attn_kernel<<<dim3(32, 32), 256, 0, stream>>>(
        QKV, QKV + (size_t)8192 * 256, QKV + (size_t)2 * 8192 * 256, Ab);

    gemm_out_kernel<<<dim3(2, 128), 256, 0, stream>>>(Ab, Wall + (size_t)3 * 65536, bo, out);
}

// Round 3
// 96.890 us; speedup vs baseline: 37.8544x; 1.2803x over previous
//
#include <hip/hip_runtime.h>
#include <math.h>

#define D_MODEL 256
#define NSEQ    2048
#define BATCH   4
#define NHEAD   8
#define HDIM    32
#define SCL2E   0.25506372769861746f   // log2(e)/sqrt(32)

typedef __attribute__((ext_vector_type(8))) short  short8;   // 8 bf16
typedef __attribute__((ext_vector_type(4))) float  f32x4;
typedef __attribute__((ext_vector_type(4))) unsigned int u32x4;
typedef __attribute__((ext_vector_type(2))) unsigned int u32x2;
typedef unsigned short u16;
typedef unsigned int   u32;

__device__ __forceinline__ u16 f2bf(float f) {                 // RNE
    union { float f; u32 u; } v; v.f = f;
    u32 r = v.u + 0x7FFFu + ((v.u >> 16) & 1u);
    return (u16)(r >> 16);
}
__device__ __forceinline__ u32 packbf(float lo, float hi) {    // ~RNE pair pack
    union { float f; u32 u; } a, b; a.f = lo; b.f = hi;
    return __builtin_amdgcn_perm(b.u + 0x8000u, a.u + 0x8000u, 0x07060302);
}
__device__ __forceinline__ float fexp2(float x) {              // raw v_exp_f32
    float r; asm("v_exp_f32 %0, %1" : "=v"(r) : "v"(x)); return r;
}

// ---------------------------------------------------------------------------
// fp32 -> bf16: x (262144 groups of 8) then the 4 weight matrices (32768 groups)
// ---------------------------------------------------------------------------
__global__ __launch_bounds__(256) void cvt_kernel(
    const float* __restrict__ x,
    const float* __restrict__ w0, const float* __restrict__ w1,
    const float* __restrict__ w2, const float* __restrict__ w3,
    u16* __restrict__ xb, u16* __restrict__ Wall)
{
    int i = blockIdx.x * 256 + threadIdx.x;
    const float* src; u16* dst; size_t off;
    if (i < 262144) { src = x; dst = xb; off = i; }
    else {
        int j = i - 262144; int which = j >> 13;
        src = which == 0 ? w0 : which == 1 ? w1 : which == 2 ? w2 : w3;
        dst = Wall + (size_t)which * 65536; off = j & 8191;
    }
    const float4* s4 = (const float4*)src;
    float4 a = s4[2 * off], b = s4[2 * off + 1];
    u32x4 o;
    o.x = (u32)f2bf(a.x) | ((u32)f2bf(a.y) << 16);
    o.y = (u32)f2bf(a.z) | ((u32)f2bf(a.w) << 16);
    o.z = (u32)f2bf(b.x) | ((u32)f2bf(b.y) << 16);
    o.w = (u32)f2bf(b.z) | ((u32)f2bf(b.w) << 16);
    *(u32x4*)(dst + off * 8) = o;
}

// ---------------------------------------------------------------------------
// Fused QKV GEMM (z = 0/1/2 -> Q/K/V).  C = x @ W^T + b, bf16 MFMA.
// Q: prescaled by SCL2E, layout (B,H,N,HD).  K: (B,H,N,HD).
// V: TRANSPOSED layout (B,H,HD,N) via LDS transpose epilogue.
// ---------------------------------------------------------------------------
__global__ __launch_bounds__(256) void gemm_qkv_kernel(
    const u16* __restrict__ xb, const u16* __restrict__ Wall,
    const float* __restrict__ bq, const float* __restrict__ bk,
    const float* __restrict__ bv,
    u16* __restrict__ Qo, u16* __restrict__ Ko, u16* __restrict__ Vto)
{
    __shared__ u16 Ls[128 * 72];
    const int z = blockIdx.z;
    const u16* W = Wall + (size_t)z * 65536;
    const float* bias = z == 0 ? bq : (z == 1 ? bk : bv);

    const int wid = threadIdx.x >> 6, l = threadIdx.x & 63;
    const int lq = l & 15, g = l >> 4;
    const int m0 = blockIdx.y * 64 + wid * 16;
    const int n0 = blockIdx.x * 128;
    const u16* Arow = xb + (size_t)(m0 + lq) * 256;

    f32x4 acc[8];
    #pragma unroll
    for (int ns = 0; ns < 8; ++ns) acc[ns] = (f32x4){0.f, 0.f, 0.f, 0.f};

    #pragma unroll
    for (int kk = 0; kk < 8; ++kk) {
        short8 af = *(const short8*)(Arow + kk * 32 + g * 8);
        #pragma unroll
        for (int ns = 0; ns < 8; ++ns) {
            short8 wf = *(const short8*)(W + (size_t)(n0 + ns * 16 + lq) * 256 + kk * 32 + g * 8);
            acc[ns] = __builtin_amdgcn_mfma_f32_16x16x32_bf16(af, wf, acc[ns], 0, 0, 0);
        }
    }

    if (z < 2) {
        const float sc = (z == 0) ? SCL2E : 1.0f;
        u16* out = (z == 0) ? Qo : Ko;
        #pragma unroll
        for (int ns = 0; ns < 8; ++ns) {
            const int n = n0 + ns * 16 + lq;
            const float bb = bias[n];
            const int h = n >> 5, dd = n & 31;
            #pragma unroll
            for (int r = 0; r < 4; ++r) {
                const int m = m0 + g * 4 + r;
                const int b = m >> 11, seq = m & 2047;
                out[((size_t)(b * 8 + h) * 2048 + seq) * 32 + dd] = f2bf((acc[ns][r] + bb) * sc);
            }
        }
    } else {
        // transpose 128n x 64m tile through LDS, emit V^T rows (d-major)
        #pragma unroll
        for (int ns = 0; ns < 8; ++ns) {
            const int nl = ns * 16 + lq;
            const float bb = bias[n0 + nl];
            #pragma unroll
            for (int r = 0; r < 4; ++r)
                Ls[nl * 72 + wid * 16 + g * 4 + r] = f2bf(acc[ns][r] + bb);
        }
        __syncthreads();
        const int t = threadIdx.x, nl = t >> 1, hf = t & 1;
        const int n = n0 + nl, h = n >> 5, dd = n & 31;
        const int m0blk = blockIdx.y * 64;
        const int b = m0blk >> 11, seq0 = (m0blk & 2047) + hf * 32;
        u16* dst = Vto + ((size_t)(b * 8 + h) * 32 + dd) * 2048 + seq0;
        #pragma unroll
        for (int c = 0; c < 4; ++c)
            *(short8*)(dst + c * 8) = *(const short8*)&Ls[nl * 72 + hf * 32 + c * 8];
    }
}

// ---------------------------------------------------------------------------
// Output GEMM: out = attended @ Wo^T + bo, fp32 stores.
// ---------------------------------------------------------------------------
__global__ __launch_bounds__(256) void gemm_out_kernel(
    const u16* __restrict__ A, const u16* __restrict__ W,
    const float* __restrict__ bias, float* __restrict__ Cout)
{
    const int wid = threadIdx.x >> 6, l = threadIdx.x & 63;
    const int lq = l & 15, g = l >> 4;
    const int m0 = blockIdx.y * 64 + wid * 16;
    const int n0 = blockIdx.x * 128;
    const u16* Arow = A + (size_t)(m0 + lq) * 256;

    f32x4 acc[8];
    #pragma unroll
    for (int ns = 0; ns < 8; ++ns) acc[ns] = (f32x4){0.f, 0.f, 0.f, 0.f};

    #pragma unroll
    for (int kk = 0; kk < 8; ++kk) {
        short8 af = *(const short8*)(Arow + kk * 32 + g * 8);
        #pragma unroll
        for (int ns = 0; ns < 8; ++ns) {
            short8 wf = *(const short8*)(W + (size_t)(n0 + ns * 16 + lq) * 256 + kk * 32 + g * 8);
            acc[ns] = __builtin_amdgcn_mfma_f32_16x16x32_bf16(af, wf, acc[ns], 0, 0, 0);
        }
    }

    #pragma unroll
    for (int ns = 0; ns < 8; ++ns) {
        const int n = n0 + ns * 16 + lq;
        const float bb = bias[n];
        #pragma unroll
        for (int r = 0; r < 4; ++r)
            Cout[(size_t)(m0 + g * 4 + r) * 256 + n] = acc[ns][r] + bb;
    }
}

// ---------------------------------------------------------------------------
// Flash attention, barrier-free. 4 independent waves/block, 32 q-rows/wave
// (two 16-row subtiles sharing K/V fragments). K fragments from global
// (L2-resident), V fragments from global V^T. Only P round-trips through LDS.
// Softmax: scores arrive as s*log2e/sqrt(32) - m via MFMA C-input; p=exp2(sf);
// row-sums via MFMA against a ones-fragment into a 3rd accumulator.
// ---------------------------------------------------------------------------
__global__ __launch_bounds__(256) void attn_kernel(
    const u16* __restrict__ Q, const u16* __restrict__ K,
    const u16* __restrict__ Vt, u16* __restrict__ Oa)
{
    __shared__ u16 Pl[4][2][16 * 72];

    const int tid = threadIdx.x, wid = tid >> 6, l = tid & 63;
    const int lq = l & 15, g = l >> 4;
    const int bh = blockIdx.y;
    const int q0 = blockIdx.x * 128 + wid * 32;

    const u16* Qb = Q  + ((size_t)bh * 2048 + q0) * 32;
    const u16* Kb = K  + (size_t)bh * 2048 * 32;
    const u16* Vb = Vt + (size_t)bh * 32 * 2048;

    const short8 qfa = *(const short8*)(Qb + lq * 32 + g * 8);
    const short8 qfb = *(const short8*)(Qb + (16 + lq) * 32 + g * 8);
    const short8 ones8 = {16256,16256,16256,16256,16256,16256,16256,16256}; // bf16 1.0

    f32x4 oa0 = (f32x4){0,0,0,0}, oa1 = oa0, oa2 = oa0;
    f32x4 ob0 = oa0, ob1 = oa0, ob2 = oa0;
    float ma = -1024.0f, mb = -1024.0f;

    auto loadK = [&](int kt, short8 (&dst)[4]) {
        const u16* p = Kb + (size_t)kt * 64 * 32;
        #pragma unroll
        for (int s = 0; s < 4; ++s)
            dst[s] = *(const short8*)(p + (s * 16 + lq) * 32 + g * 8);
    };
    auto loadV = [&](int kt, short8 (&dst)[2][2]) {
        #pragma unroll
        for (int hh = 0; hh < 2; ++hh)
            #pragma unroll
            for (int kc = 0; kc < 2; ++kc)
                dst[hh][kc] = *(const short8*)(Vb + (size_t)(hh * 16 + lq) * 2048
                                               + kt * 64 + kc * 32 + g * 8);
    };

    auto proc = [&](const short8& qf, short8 (&kf)[4], short8 (&vf)[2][2],
                    f32x4& o0, f32x4& o1, f32x4& o2, float& m, u16* PlW) {
        const f32x4 nm = (f32x4){-m, -m, -m, -m};
        f32x4 sf[4];
        #pragma unroll
        for (int s = 0; s < 4; ++s)
            sf[s] = __builtin_amdgcn_mfma_f32_16x16x32_bf16(kf[s], qf, nm, 0, 0, 0);

        float t0 = fmaxf(fmaxf(sf[0][0], sf[0][1]), fmaxf(sf[0][2], sf[0][3]));
        float t1 = fmaxf(fmaxf(sf[1][0], sf[1][1]), fmaxf(sf[1][2], sf[1][3]));
        float t2 = fmaxf(fmaxf(sf[2][0], sf[2][1]), fmaxf(sf[2][2], sf[2][3]));
        float t3 = fmaxf(fmaxf(sf[3][0], sf[3][1]), fmaxf(sf[3][2], sf[3][3]));
        float tm = fmaxf(fmaxf(t0, t1), fmaxf(t2, t3));
        tm = fmaxf(tm, __shfl_xor(tm, 16));
        tm = fmaxf(tm, __shfl_xor(tm, 32));

        if (__any(tm > 8.0f)) {            // rare rescale path (tile 0, outliers)
            const float d = fmaxf(tm, 0.f);
            m += d;
            const float scl = fexp2(-d);
            #pragma unroll
            for (int r = 0; r < 4; ++r) {
                const float sr = __shfl(scl, g * 4 + r);
                o0[r] *= sr; o1[r] *= sr; o2[r] *= sr;
            }
            #pragma unroll
            for (int s = 0; s < 4; ++s) {
                float p0 = fexp2(sf[s][0] - d), p1 = fexp2(sf[s][1] - d);
                float p2 = fexp2(sf[s][2] - d), p3 = fexp2(sf[s][3] - d);
                u32x2 w; w.x = packbf(p0, p1); w.y = packbf(p2, p3);
                *(u32x2*)&PlW[lq * 72 + s * 16 + g * 4] = w;
            }
        } else {                            // fast path: no subtract at all
            #pragma unroll
            for (int s = 0; s < 4; ++s) {
                float p0 = fexp2(sf[s][0]), p1 = fexp2(sf[s][1]);
                float p2 = fexp2(sf[s][2]), p3 = fexp2(sf[s][3]);
                u32x2 w; w.x = packbf(p0, p1); w.y = packbf(p2, p3);
                *(u32x2*)&PlW[lq * 72 + s * 16 + g * 4] = w;
            }
        }

        #pragma unroll
        for (int kc = 0; kc < 2; ++kc) {
            short8 pa = *(const short8*)&PlW[lq * 72 + kc * 32 + g * 8];
            o0 = __builtin_amdgcn_mfma_f32_16x16x32_bf16(pa, vf[0][kc], o0, 0, 0, 0);
            o1 = __builtin_amdgcn_mfma_f32_16x16x32_bf16(pa, vf[1][kc], o1, 0, 0, 0);
            o2 = __builtin_amdgcn_mfma_f32_16x16x32_bf16(pa, ones8,    o2, 0, 0, 0);
        }
    };

    short8 kfA[4], kfB[4];
    short8 vfA[2][2], vfB[2][2];
    loadK(0, kfA); loadV(0, vfA);

    auto body = [&](int kt, short8 (&ck)[4], short8 (&cv)[2][2],
                    short8 (&nk)[4], short8 (&nv)[2][2]) {
        const int ktn = (kt + 1 < 32) ? kt + 1 : 31;
        loadK(ktn, nk); loadV(ktn, nv);
        proc(qfa, ck, cv, oa0, oa1, oa2, ma, &Pl[wid][0][0]);
        proc(qfb, ck, cv, ob0, ob1, ob2, mb, &Pl[wid][1][0]);
    };

    for (int kt = 0; kt < 32; kt += 2) {
        body(kt,     kfA, vfA, kfB, vfB);
        body(kt + 1, kfB, vfB, kfA, vfA);
    }

    const int b = bh >> 3, h = bh & 7;
    #pragma unroll
    for (int r = 0; r < 4; ++r) {
        const float inva = __builtin_amdgcn_rcpf(oa2[r]);
        const float invb = __builtin_amdgcn_rcpf(ob2[r]);
        const int seqa = q0 + g * 4 + r, seqb = seqa + 16;
        const size_t ba = ((size_t)(b * 2048 + seqa)) * 256 + h * 32;
        const size_t bb2 = ((size_t)(b * 2048 + seqb)) * 256 + h * 32;
        Oa[ba + lq]       = f2bf(oa0[r] * inva);
        Oa[ba + 16 + lq]  = f2bf(oa1[r] * inva);
        Oa[bb2 + lq]      = f2bf(ob0[r] * invb);
        Oa[bb2 + 16 + lq] = f2bf(ob1[r] * invb);
    }
}

// ---------------------------------------------------------------------------
extern "C" void kernel_launch(void* const* d_in, const int* in_sizes, int n_in,
                              void* d_out, int out_size, void* d_ws, size_t ws_size,
                              hipStream_t stream)
{
    const float* x  = (const float*)d_in[0];
    const float* Wq = (const float*)d_in[1];
    const float* bq = (const float*)d_in[2];
    const float* Wk = (const float*)d_in[3];
    const float* bk = (const float*)d_in[4];
    const float* Wv = (const float*)d_in[5];
    const float* bv = (const float*)d_in[6];
    const float* Wo = (const float*)d_in[7];
    const float* bo = (const float*)d_in[8];
    float* out = (float*)d_out;

    u16* wsp  = (u16*)d_ws;
    u16* xb   = wsp;                            // 8192*256
    u16* Wall = xb + (size_t)8192 * 256;        // 4*65536
    u16* Qh   = Wall + (size_t)4 * 65536;       // (B,H,N,HD)
    u16* Kh   = Qh + (size_t)8192 * 256;        // (B,H,N,HD)
    u16* Vth  = Kh + (size_t)8192 * 256;        // (B,H,HD,N)
    u16* Ab   = Vth + (size_t)8192 * 256;       // (B,N,D)

    cvt_kernel<<<1152, 256, 0, stream>>>(x, Wq, Wk, Wv, Wo, xb, Wall);
    gemm_qkv_kernel<<<dim3(2, 128, 3), 256, 0, stream>>>(xb, Wall, bq, bk, bv, Qh, Kh, Vth);
    attn_kernel<<<dim3(16, 32), 256, 0, stream>>>(Qh, Kh, Vth, Ab);
    gemm_out_kernel<<<dim3(2, 128), 256, 0, stream>>>(Ab, Wall + (size_t)3 * 65536, bo, out);
}